// Round 5
// baseline (455.176 us; speedup 1.0000x reference)
//
#include <hip/hip_runtime.h>
#include <math.h>

// x = (16, 32, 65536) fp32. Per-row std -> threshold -> damp -> recombine, x2.
// cur2 (the iter-1 output) is NEVER materialized: pass2 computes its stats and
// discards it; pass3 recomputes it from x on the fly. HBM traffic = cold x read
// + 2 L3-hot x re-reads + nontemporal out write. 5 launches, zero LDS/barriers.
//   k_stats1 (read x)          -> partials of (r1, r1^2)
//   k_thr                      -> th1[512]   (one 64-lane block per row)
//   k_stats2 (read x, no store)-> cur2 locally, partials of (r2, r2^2)
//   k_thr                      -> th2[512]
//   k_final  (read x, write out)-> recompute cur2 ext, out = iter2, nt stores

#define LROW  65536
#define NROWS 512
#define NT    256
#define TPE   8                      // elements per thread
#define EPB   (NT * TPE)             // 2048 elements per block
#define BPR   (LROW / EPB)           // 32 blocks per row
#define GRID  (NROWS * BPR)          // 16384 blocks
#define WPB   (NT / 64)              // 4 waves per block
#define PPR   (BPR * WPB)            // 128 partials per row

#define TS 0.6f
#define DP 0.85f
#define SD 0.35f

typedef float floatx4 __attribute__((ext_vector_type(4)));

__device__ __forceinline__ int refl(int g) {
    return g < 0 ? -g : (g >= LROW ? 2 * LROW - 2 - g : g);
}

__device__ __forceinline__ void wave_reduce_store(double s, double q, int tid,
                                                  int bid, double2* parts) {
#pragma unroll
    for (int off = 32; off; off >>= 1) {
        s += __shfl_down(s, off);
        q += __shfl_down(q, off);
    }
    if ((tid & 63) == 0) {
        double2 v; v.x = s; v.y = q;
        parts[(size_t)bid * WPB + (tid >> 6)] = v;
    }
}

// ---- pass 1: stats of r1 = x - local5(x). 16 floats/thread. ----
__global__ __launch_bounds__(NT) void k_stats1(const float* __restrict__ x,
                                               const float* __restrict__ k5p,
                                               double2* __restrict__ parts) {
    const int bid = blockIdx.x, tid = threadIdx.x;
    const int row = bid / BPR, ck = bid % BPR;
    const float* rp = x + (size_t)row * LROW;
    const int t = ck * EPB + tid * TPE;
    const float w5 = k5p[0];

    float f[16];  // x[t-4 .. t+11]
    if (t >= 4 && t + 12 <= LROW) {
        const float4* p4 = (const float4*)(rp + t - 4);
#pragma unroll
        for (int i = 0; i < 4; i++) {
            float4 u = p4[i];
            f[4 * i] = u.x; f[4 * i + 1] = u.y; f[4 * i + 2] = u.z; f[4 * i + 3] = u.w;
        }
    } else {
#pragma unroll
        for (int i = 0; i < 16; i++) f[i] = rp[refl(t - 4 + i)];
    }

    double s = 0.0, q = 0.0;
#pragma unroll
    for (int k = 0; k < TPE; k++) {
        float loc = 0.f;
#pragma unroll
        for (int d = 0; d < 5; d++) loc = fmaf(f[k + 2 + d], w5, loc);
        float r = f[k + 4] - loc;
        s += (double)r;
        q += (double)r * (double)r;
    }
    wave_reduce_store(s, q, tid, bid, parts);
}

// ---- per-row threshold: one 64-lane block per row, coalesced + butterfly ----
__global__ __launch_bounds__(64) void k_thr(const double2* __restrict__ parts,
                                            float* __restrict__ th) {
    const int r = blockIdx.x, lane = threadIdx.x;
    const double2* p = parts + (size_t)r * PPR;
    double2 a = p[lane], b = p[lane + 64];
    double s = a.x + b.x, q = a.y + b.y;
#pragma unroll
    for (int off = 32; off; off >>= 1) {
        s += __shfl_down(s, off);
        q += __shfl_down(q, off);
    }
    if (lane == 0) {
        const double N = (double)LROW;
        double var = (q - s * s / N) / (N - 1.0);
        if (var < 0.0) var = 0.0;
        th[r] = fmaxf((float)sqrt(var), 1e-6f) * 3.5f;
    }
}

// ---- pass 2: cur2 = iter1(x) at positions [t-2, t+9] (held in regs only);
//      stats of r2 = cur2 - local5(cur2). x halo 7 -> 24 floats/thread. ----
__global__ __launch_bounds__(NT) void k_stats2(const float* __restrict__ x,
                                               const float* __restrict__ k5p,
                                               const float* __restrict__ k11p,
                                               const float* __restrict__ th1,
                                               double2* __restrict__ parts2) {
    const int bid = blockIdx.x, tid = threadIdx.x;
    const int row = bid / BPR, ck = bid % BPR;
    const float* rp = x + (size_t)row * LROW;
    const int t = ck * EPB + tid * TPE;
    const float w5 = k5p[0], w11 = k11p[0], th = th1[row];

    float f[24];  // x[t-8 .. t+15]
    if (t >= 8 && t + 16 <= LROW) {
        const float4* p4 = (const float4*)(rp + t - 8);
#pragma unroll
        for (int i = 0; i < 6; i++) {
            float4 u = p4[i];
            f[4 * i] = u.x; f[4 * i + 1] = u.y; f[4 * i + 2] = u.z; f[4 * i + 3] = u.w;
        }
    } else {
#pragma unroll
        for (int i = 0; i < 24; i++) f[i] = rp[refl(t - 8 + i)];
    }

    float c2[12];  // cur2 at p = t-2+j
#pragma unroll
    for (int j = 0; j < 12; j++) {
        float trend = 0.f, loc = 0.f;
#pragma unroll
        for (int d = 0; d < 11; d++) trend = fmaf(f[j + 1 + d], w11, trend);
#pragma unroll
        for (int d = 0; d < 5; d++) loc = fmaf(f[j + 4 + d], w5, loc);
        float r = f[j + 6] - loc;
        r = (fabsf(r) > th) ? r * SD : r;
        c2[j] = (1.0f - TS) * loc + TS * trend + DP * r;
    }

    double s = 0.0, q = 0.0;
#pragma unroll
    for (int k = 0; k < TPE; k++) {
        float loc = 0.f;
#pragma unroll
        for (int d = 0; d < 5; d++) loc = fmaf(c2[k + d], w5, loc);
        float r = c2[k + 2] - loc;
        s += (double)r;
        q += (double)r * (double)r;
    }
    wave_reduce_store(s, q, tid, bid, parts2);
}

// ---- pass 3: recompute cur2 at [t-8, t+15] from x (span x[t-16..t+23]),
//      then out = iter2(cur2). Nontemporal final stores. ----
__global__ __launch_bounds__(NT) void k_final(const float* __restrict__ x,
                                              float* __restrict__ out,
                                              const float* __restrict__ k5p,
                                              const float* __restrict__ k11p,
                                              const float* __restrict__ th1,
                                              const float* __restrict__ th2) {
    const int bid = blockIdx.x, tid = threadIdx.x;
    const int row = bid / BPR, ck = bid % BPR;
    const float* rp = x + (size_t)row * LROW;
    const int t = ck * EPB + tid * TPE;
    const float w5 = k5p[0], w11 = k11p[0];
    const float tA = th1[row], tB = th2[row];

    float f[40];  // x[t-16 .. t+23]
    if (t >= 16 && t + 24 <= LROW) {
        const float4* p4 = (const float4*)(rp + t - 16);
#pragma unroll
        for (int i = 0; i < 10; i++) {
            float4 u = p4[i];
            f[4 * i] = u.x; f[4 * i + 1] = u.y; f[4 * i + 2] = u.z; f[4 * i + 3] = u.w;
        }
    } else {
#pragma unroll
        for (int i = 0; i < 40; i++) f[i] = rp[refl(t - 16 + i)];
    }

    float c2[24];  // cur2 at p = t-8+j, needs x[p-5..p+5] = f[j+3..j+13]
#pragma unroll
    for (int j = 0; j < 24; j++) {
        float trend = 0.f, loc = 0.f;
#pragma unroll
        for (int d = 0; d < 11; d++) trend = fmaf(f[j + 3 + d], w11, trend);
#pragma unroll
        for (int d = 0; d < 5; d++) loc = fmaf(f[j + 6 + d], w5, loc);
        float r = f[j + 8] - loc;
        r = (fabsf(r) > tA) ? r * SD : r;
        c2[j] = (1.0f - TS) * loc + TS * trend + DP * r;
    }

    float o[TPE];
#pragma unroll
    for (int k = 0; k < TPE; k++) {
        float trend = 0.f, loc = 0.f;
#pragma unroll
        for (int d = 0; d < 11; d++) trend = fmaf(c2[k + 3 + d], w11, trend);
#pragma unroll
        for (int d = 0; d < 5; d++) loc = fmaf(c2[k + 6 + d], w5, loc);
        float r = c2[k + 8] - loc;
        r = (fabsf(r) > tB) ? r * SD : r;
        o[k] = (1.0f - TS) * loc + TS * trend + DP * r;
    }

    floatx4* op = (floatx4*)(out + (size_t)row * LROW + t);
    floatx4 v0 = { o[0], o[1], o[2], o[3] };
    floatx4 v1 = { o[4], o[5], o[6], o[7] };
    __builtin_nontemporal_store(v0, op);
    __builtin_nontemporal_store(v1, op + 1);
}

extern "C" void kernel_launch(void* const* d_in, const int* in_sizes, int n_in,
                              void* d_out, int out_size, void* d_ws, size_t ws_size,
                              hipStream_t stream) {
    const float* x   = (const float*)d_in[0];
    const float* k5  = (const float*)d_in[1];
    const float* k11 = (const float*)d_in[2];
    float* out = (float*)d_out;

    // ws layout: parts1 (1 MiB) | parts2 (1 MiB) | th1 | th2
    double2* p1  = (double2*)d_ws;
    double2* p2  = p1 + (size_t)GRID * WPB;
    float*   th1 = (float*)(p2 + (size_t)GRID * WPB);
    float*   th2 = th1 + NROWS;

    hipLaunchKernelGGL(k_stats1, dim3(GRID), dim3(NT), 0, stream, x, k5, p1);
    hipLaunchKernelGGL(k_thr, dim3(NROWS), dim3(64), 0, stream, p1, th1);
    hipLaunchKernelGGL(k_stats2, dim3(GRID), dim3(NT), 0, stream,
                       x, k5, k11, th1, p2);
    hipLaunchKernelGGL(k_thr, dim3(NROWS), dim3(64), 0, stream, p2, th2);
    hipLaunchKernelGGL(k_final, dim3(GRID), dim3(NT), 0, stream,
                       x, out, k5, k11, th1, th2);
}